// Round 7
// baseline (359.144 us; speedup 1.0000x reference)
//
#include <hip/hip_runtime.h>
#include <math.h>

// ---------------------------------------------------------------------------
// R-GCN (basis decomposition, B=2), 2 layers.
//   C[n, 0:192] = x[n,:] @ [loop_w | basis0 | basis1]   (dense, MFMA bf16x3)
//   self = C[:,0:64]+bias ;  hb2[n][j] = (C[n,64+j], C[n,128+j])  (float2)
//   out[n] = act(self[n] + sum_{e: dst=n} c0*hb2[src][j].x + c1*hb2[src][j].y)
//
// Dense via matrix cores with fp32 emulation: x = xh + xl, w = wh + wl
// (bf16 hi/lo, RNE); C = xh*wh + xh*wl + xl*wh  (xl*wl ~ 2^-18, dropped).
// Edge aggregation via per-dst LINKED LIST (no CSR, no random 4B scatter):
//   build: prev = atomicExch(head[dst], e+1); rec[e] = prev<<23|src<<6|et
//   (record write coalesced by e); agg walks the chain per node.
// ---------------------------------------------------------------------------

typedef short          short8 __attribute__((ext_vector_type(8)));
typedef float          f32x4  __attribute__((ext_vector_type(4)));
typedef unsigned short u16;
typedef unsigned long long u64;

static __device__ __forceinline__ u16 bf16_rne(float x) {
    unsigned u = __float_as_uint(x);
    return (u16)((u + 0x7fffu + ((u >> 16) & 1u)) >> 16);
}
static __device__ __forceinline__ float bf16_f32(u16 h) {
    return __uint_as_float(((unsigned)h) << 16);
}

// ---------------- W pre-convert: Wt[192][K] bf16 hi/lo (transposed) --------
__global__ __launch_bounds__(256) void wconv(
    const float* __restrict__ loopw1, const float* __restrict__ basis1,
    const float* __restrict__ loopw2, const float* __restrict__ basis2,
    u16* __restrict__ wt1h, u16* __restrict__ wt1l,
    u16* __restrict__ wt2h, u16* __restrict__ wt2l)
{
    const int tid = blockIdx.x * 256 + threadIdx.x;
    if (tid < 192 * 128) {                       // layer 1, K=128
        const int j = tid >> 7, k = tid & 127;
        const float w = (j < 64)
            ? loopw1[k * 64 + j]
            : basis1[(size_t)((j - 64) >> 6) * (128 * 64) + k * 64 + ((j - 64) & 63)];
        const u16 h = bf16_rne(w);
        wt1h[tid] = h;
        wt1l[tid] = bf16_rne(w - bf16_f32(h));
    }
    if (tid < 192 * 64) {                        // layer 2, K=64
        const int j = tid >> 6, k = tid & 63;
        const float w = (j < 64)
            ? loopw2[k * 64 + j]
            : basis2[(size_t)((j - 64) >> 6) * (64 * 64) + k * 64 + ((j - 64) & 63)];
        const u16 h = bf16_rne(w);
        wt2h[tid] = h;
        wt2l[tid] = bf16_rne(w - bf16_f32(h));
    }
}

// ---------------- dense: 128 nodes/block, 8 waves, W in LDS ----------------
template<int K>
__global__ __launch_bounds__(512, 2) void rgcn_dense_mfma(
    const float* __restrict__ x,     // [N][K] f32
    const u16* __restrict__ wth,     // [192][K] bf16 hi (transposed)
    const u16* __restrict__ wtl,     // [192][K] bf16 lo
    const float* __restrict__ bias,  // [64]
    float* __restrict__ self,        // [N][64]  = x@loopw + bias
    float2* __restrict__ hb2,        // [N][64]  = (x@basis0, x@basis1) pairs
    int nNodes)
{
    constexpr int KC  = K / 32;          // mfma K-steps
    constexpr int GW  = K / 8;           // 16B granules per (col,split)
    constexpr int GMW = GW - 1;          // granule XOR mask
    __shared__ u16 wlds[96 * 2 * K];     // one 96-col half of W (hi+lo)

    const int n0   = blockIdx.x * 128;
    const int lane = threadIdx.x & 63;
    const int w    = threadIdx.x >> 6;   // 0..7
    const int rl   = lane & 15;          // A row / B col / D col
    const int kb   = lane >> 4;          // k-block

    // ---- A fragments: global -> reg, convert to bf16 hi/lo ----
    const int row = n0 + w * 16 + rl;
    short8 Ah[KC], Al[KC];
    #pragma unroll
    for (int kc = 0; kc < KC; ++kc) {
        float v[8];
        if (row < nNodes) {
            const float* xp = x + (size_t)row * K + kc * 32 + kb * 8;
            const float4 a = *reinterpret_cast<const float4*>(xp);
            const float4 b = *reinterpret_cast<const float4*>(xp + 4);
            v[0] = a.x; v[1] = a.y; v[2] = a.z; v[3] = a.w;
            v[4] = b.x; v[5] = b.y; v[6] = b.z; v[7] = b.w;
        } else {
            #pragma unroll
            for (int i = 0; i < 8; ++i) v[i] = 0.f;
        }
        #pragma unroll
        for (int i = 0; i < 8; ++i) {
            const u16 h = bf16_rne(v[i]);
            Ah[kc][i] = (short)h;
            Al[kc][i] = (short)bf16_rne(v[i] - bf16_f32(h));
        }
    }

    f32x4 acc[12];
    #pragma unroll
    for (int j = 0; j < 12; ++j) acc[j] = (f32x4){0.f, 0.f, 0.f, 0.f};

    #pragma unroll
    for (int hf = 0; hf < 2; ++hf) {
        if (hf) __syncthreads();         // protect LDS before overwrite
        // ---- stage 96 cols of W (hi+lo) into LDS, XOR-swizzled ----
        for (int gi = threadIdx.x; gi < 96 * 2 * GW; gi += 512) {
            const int ch = gi / (2 * GW);
            const int r  = gi - ch * 2 * GW;
            const int s  = r / GW;
            const int g  = r - s * GW;
            const u16* sp = (s == 0 ? wth : wtl)
                          + (size_t)(hf * 96 + ch) * K + g * 8;
            const short8 vv = *reinterpret_cast<const short8*>(sp);
            *reinterpret_cast<short8*>(
                &wlds[((ch * 2 + s) * GW + (g ^ (ch & GMW))) * 8]) = vv;
        }
        __syncthreads();

        #pragma unroll
        for (int j16h = 0; j16h < 6; ++j16h) {
            const int ch = j16h * 16 + rl;
            const u16* bbase = &wlds[(ch * 2) * GW * 8];
            #pragma unroll
            for (int kc = 0; kc < KC; ++kc) {
                const int gp = (kc * 4 + kb) ^ (ch & GMW);
                const short8 Bh =
                    *reinterpret_cast<const short8*>(bbase + gp * 8);
                const short8 Bl =
                    *reinterpret_cast<const short8*>(bbase + (GW + gp) * 8);
                f32x4 a = acc[hf * 6 + j16h];
                a = __builtin_amdgcn_mfma_f32_16x16x32_bf16(Ah[kc], Bh, a, 0, 0, 0);
                a = __builtin_amdgcn_mfma_f32_16x16x32_bf16(Ah[kc], Bl, a, 0, 0, 0);
                a = __builtin_amdgcn_mfma_f32_16x16x32_bf16(Al[kc], Bh, a, 0, 0, 0);
                acc[hf * 6 + j16h] = a;
            }
        }
    }

    // ---- epilogue: D[(kb*4+r)][rl] ----
    const int rowbase = n0 + w * 16 + kb * 4;
    #pragma unroll
    for (int j16 = 0; j16 < 4; ++j16) {          // cols 0..63 -> self + bias
        const float bj = bias[j16 * 16 + rl];
        #pragma unroll
        for (int r = 0; r < 4; ++r) {
            const int rr = rowbase + r;
            if (rr < nNodes)
                self[(size_t)rr * 64 + j16 * 16 + rl] = acc[j16][r] + bj;
        }
    }
    #pragma unroll
    for (int j16 = 4; j16 < 8; ++j16) {          // (basis0, basis1) pairs
        #pragma unroll
        for (int r = 0; r < 4; ++r) {
            const int rr = rowbase + r;
            if (rr < nNodes)
                hb2[(size_t)rr * 64 + (j16 - 4) * 16 + rl] =
                    make_float2(acc[j16][r], acc[j16 + 4][r]);
        }
    }
}

// ---------------- linked-list build (replaces whole CSR build) -------------
// head[n] = (last edge e with dst==n) + 1, 0 if none.
// rec[e]  = prev_head(21b) << 23 | src(17b) << 6 | et(6b)   -- write coalesced
__global__ __launch_bounds__(256) void ll_build(
    const int* __restrict__ src, const int* __restrict__ dst,
    const int* __restrict__ et, int* __restrict__ head,
    u64* __restrict__ rec, int nE)
{
    const int e = blockIdx.x * 256 + threadIdx.x;
    if (e < nE) {
        const int prev = atomicExch(&head[dst[e]], e + 1);
        rec[e] = ((u64)(unsigned)prev << 23)
               | ((u64)(unsigned)src[e] << 6)
               | (u64)(unsigned)et[e];
    }
}

// ---------------- edge aggregation: one wave per dst node ------------------
template<int ACT>   // 0 = tanh, 1 = relu
__global__ __launch_bounds__(256) void rgcn_agg(
    const float2* __restrict__ hb2,     // [N][64] float2 (b0,b1)
    const float* __restrict__ comp,     // [R][2]
    const int* __restrict__ head,       // [N]
    const u64* __restrict__ rec,        // [E]
    float* __restrict__ io,             // in: self+bias, out: act(self+agg)
    int nNodes)
{
    const int lane = threadIdx.x & 63;
    const int w  = (blockIdx.x * 256 + threadIdx.x) >> 6;
    const int nW = (gridDim.x * 256) >> 6;
    const float2* __restrict__ comp2 = reinterpret_cast<const float2*>(comp);
    for (int n = w; n < nNodes; n += nW) {
        const float self = io[(size_t)n * 64 + lane];   // issue early
        float acc0 = 0.f, acc1 = 0.f;
        int e1 = head[n];                               // wave-uniform
        while (e1) {
            const u64 r = rec[e1 - 1];                  // uniform 8B broadcast
            e1 = (int)(r >> 23);
            const int s = (int)((r >> 6) & 0x1FFFFu);
            const float2 cc = comp2[r & 63u];
            const float2 v = hb2[(size_t)s * 64 + lane]; // 512B/wave gather
            acc0 = fmaf(cc.x, v.x, acc0);
            acc1 = fmaf(cc.y, v.y, acc1);
        }
        float o = self + acc0 + acc1;
        o = (ACT == 0) ? tanhf(o) : fmaxf(o, 0.f);
        io[(size_t)n * 64 + lane] = o;
    }
}

// ---------------------------------------------------------------------------
extern "C" void kernel_launch(void* const* d_in, const int* in_sizes, int n_in,
                              void* d_out, int out_size, void* d_ws, size_t ws_size,
                              hipStream_t stream)
{
    const float* node_emb = (const float*)d_in[0];   // [N][128]
    const float* basis1   = (const float*)d_in[1];   // [2][128][64]
    const float* comp1    = (const float*)d_in[2];   // [R][2]
    const float* loop_w1  = (const float*)d_in[3];   // [128][64]
    const float* bias1    = (const float*)d_in[4];   // [64]
    const float* basis2   = (const float*)d_in[5];   // [2][64][64]
    const float* comp2    = (const float*)d_in[6];   // [R][2]
    const float* loop_w2  = (const float*)d_in[7];   // [64][64]
    const float* bias2    = (const float*)d_in[8];   // [64]
    const int*   src      = (const int*)d_in[9];     // [E]
    const int*   dst      = (const int*)d_in[10];    // [E]
    const int*   et       = (const int*)d_in[11];    // [E]

    const int N = in_sizes[0] / 128;
    const int E = in_sizes[9];

    float* out = (float*)d_out;                      // [N][64]

    // workspace layout (8B alignment for rec holds: offsets are 8B multiples)
    float*  hb   = (float*)d_ws;                     // N*128 f (as float2 [N][64])
    float*  h    = hb + (size_t)N * 128;             // N*64 f
    u64*    rec  = (u64*)(h + (size_t)N * 64);       // E u64
    int*    head = (int*)(rec + E);                  // N
    u16*    wt1h = (u16*)(head + N);                 // 192*128
    u16*    wt1l = wt1h + 192 * 128;
    u16*    wt2h = wt1l + 192 * 128;                 // 192*64
    u16*    wt2l = wt2h + 192 * 64;

    const int nBlkDense = (N + 127) / 128;
    const int nBlkE     = (E + 255) / 256;
    const int nBlkAgg   = (N + 3) / 4;               // 1 wave per node

    // ---- W pre-convert (bf16 hi/lo, transposed) ----
    wconv<<<96, 256, 0, stream>>>(loop_w1, basis1, loop_w2, basis2,
                                  wt1h, wt1l, wt2h, wt2l);

    // ---- per-dst linked list (shared by both layers) ----
    hipMemsetAsync(head, 0, (size_t)N * sizeof(int), stream);
    ll_build<<<nBlkE, 256, 0, stream>>>(src, dst, et, head, rec, E);

    // ---- layer 1 ----
    rgcn_dense_mfma<128><<<nBlkDense, 512, 0, stream>>>(
        node_emb, wt1h, wt1l, bias1, h, (float2*)hb, N);
    rgcn_agg<0><<<nBlkAgg, 256, 0, stream>>>(
        (const float2*)hb, comp1, head, rec, h, N);

    // ---- layer 2 ----
    rgcn_dense_mfma<64><<<nBlkDense, 512, 0, stream>>>(
        h, wt2h, wt2l, bias2, out, (float2*)hb, N);
    rgcn_agg<1><<<nBlkAgg, 256, 0, stream>>>(
        (const float2*)hb, comp2, head, rec, out, N);
}